// Round 7
// baseline (58.513 us; speedup 1.0000x reference)
//
#include <hip/hip_runtime.h>

#define BROWS 524288
#define KBINS 64
#define GRID1 2048
#define RPB   64                       // rows per block per iter (4 waves * 16)
#define ITERS (BROWS / (GRID1 * RPB))  // = 4

typedef float v4f __attribute__((ext_vector_type(4)));

// Single kernel. Count stores use the aligned shifted-window scheme (round 6).
// Scalar loss: per-block partial -> packed fixed-point u64 atomicAdd
// (count in bits 52+, biased sum in bits 0..51). The block that completes the
// count derives the exact total from old+mine and writes out[0]. No fences.
__global__ __launch_bounds__(256) void surv_main(
    const float* __restrict__ inp, const float* __restrict__ yv,
    const int* __restrict__ ev, float* __restrict__ out,
    unsigned long long* __restrict__ acc64)
{
  const int tid  = threadIdx.x;
  const int lane = tid & 63;
  const int wave = tid >> 6;   // 0..3
  const int sub  = lane >> 4;  // 0..3: row-within-phase
  const int l16  = lane & 15;  // lane within 16-lane row group

  const float A   = 2.8853900817779268f;   // 2*log2(e)
  const float M2  = 0.28853900817779268f;  // 0.2*log2(e)
  const float S0  = 0.018315638888734179f; // exp(-4)
  const float IS0 = 54.598150033144236f;   // exp(+4)
  const float LN2 = 0.6931471805599453f;

  float acc = 0.f;

  // prefetch phase 0 of iter 0
  {
  }
  int pf_row = blockIdx.x * RPB + wave * 16 + sub;
  v4f xA = *reinterpret_cast<const v4f*>(inp + (size_t)pf_row * KBINS + l16 * 4);

  for (int it = 0; it < ITERS; ++it) {
    const int base = (it * GRID1 + blockIdx.x) * RPB + wave * 16;

    // 16-row y/e window: one lane-vector load each (replaces 32 scalar loads)
    const float y_all = yv[base + l16];
    const int   e_all = ev[base + l16];
    const int   bm1 = (base > 0) ? base - 1 : 0;
    const float ym1 = yv[bm1];
    const int   em1 = ev[bm1];

    // c63 (count of bin 63) for each window row; lane l16 holds row base+l16
    const bool  v_all   = (y_all >= 0.f) && (y_all < 64.f);
    const float c63_all = (e_all != 0) ? ((v_all && y_all >= 63.f) ? 1.f : 0.f)
                                       : (v_all ? 1.f : 0.f);
    const bool  vm1   = (ym1 >= 0.f) && (ym1 < 64.f);
    const float c63m1 = (em1 != 0) ? ((vm1 && ym1 >= 63.f) ? 1.f : 0.f)
                                   : (vm1 ? 1.f : 0.f);

    #pragma unroll
    for (int h = 0; h < 4; ++h) {
      // prefetch next phase's x (next iter's phase 0 on h==3; clamp at end)
      int nrow;
      if (h < 3) {
        nrow = base + (h + 1) * 4 + sub;
      } else {
        nrow = ((it + 1) * GRID1 + blockIdx.x) * RPB + wave * 16 + sub;
        if (nrow >= BROWS) nrow = BROWS - 1;   // dummy on final iter
      }
      const v4f xB = *reinterpret_cast<const v4f*>(
          inp + (size_t)nrow * KBINS + l16 * 4);

      const int g   = h * 4 + sub;   // row index within window (per-lane)
      const int row = base + g;
      const float y = __shfl(y_all, g, 64);
      const int   e = __shfl(e_all, g, 64);
      const float c63w = __shfl(c63_all, g - 1, 64);  // g==0 pulls lane63: masked below
      const float c63p = (g == 0) ? c63m1 : c63w;     // prev row's bin-63 count

      const int  b = (int)y;
      const bool valid = (y >= 0.f) && (y < 64.f);
      const int  b_eff = valid ? b : 127;             // sentinel: c==0 everywhere
      const int  hi    = (e != 0) ? b_eff : 63;       // count = [b_eff, hi]
      const bool all1  = (e == 0) && (b_eff == 0);    // all-ones -> min==1
      const float m_in = all1 ? M2 : 0.f;

      const float xa[4] = {xA.x, xA.y, xA.z, xA.w};
      float correct = 0.f, fev = 0.f, fcs = 0.f;
      float c[4];
      #pragma unroll
      for (int j = 0; j < 4; ++j) {
        const int bin = l16 * 4 + j;
        const bool cb = (bin >= b_eff) && (bin <= hi);
        const float mm = cb ? m_in : M2;
        const float t  = fmaf(xa[j], A, mm);           // log2-domain logit
        const float pen = __builtin_amdgcn_exp2f(t);   // exp(+logit)
        const float pe  = __builtin_amdgcn_exp2f(-t);  // exp(-logit)
        correct += cb ? pe  : 0.f;
        fcs     += cb ? 0.f : pe;
        fev     += cb ? 0.f : pen;
        c[j] = cb ? 1.f : 0.f;
      }

      // aligned shifted-window store: out[row*64 + l16*4 .. +3] covers count
      // bins l16*4-1..l16*4+2 of this row (cv[0] at l16==0 = prev row bin 63)
      {
        const int  binm1 = l16 * 4 - 1;
        const bool cm1 = (binm1 >= b_eff) && (binm1 <= hi);
        v4f cv;
        cv[0] = (l16 == 0) ? c63p : (cm1 ? 1.f : 0.f);
        cv[1] = c[0]; cv[2] = c[1]; cv[3] = c[2];
        float* dst = out + (size_t)row * KBINS + l16 * 4;
        if (row == 0 && l16 == 0) {
          out[1] = cv[1]; out[2] = cv[2]; out[3] = cv[3];  // out[0] = loss slot
        } else {
          *reinterpret_cast<v4f*>(dst) = cv;
        }
        if (row == BROWS - 1 && l16 == 15)
          out[(size_t)BROWS * KBINS] = c[3];               // count[B-1][63]
      }

      #pragma unroll
      for (int m = 1; m < 16; m <<= 1) {
        correct += __shfl_xor(correct, m, 64);
        fev     += __shfl_xor(fev, m, 64);
        fcs     += __shfl_xor(fcs, m, 64);
      }

      // sum(count)==1  <=>  valid && (event || b==K-1)
      const bool is_event = valid && (e != 0 || b == KBINS - 1);
      const float lev = (__builtin_amdgcn_logf(correct + S0) +
                         __builtin_amdgcn_logf(fev + S0)) * LN2;
      const float lcs = __builtin_amdgcn_logf(
                            fmaf(fcs, IS0, fmaf(correct, fcs, 1.f))) * LN2;
      if (l16 == 0) acc += is_event ? lev : lcs;

      xA = xB;
    }
  }

  // block reduction: acc nonzero at lanes {0,16,32,48}
  acc += __shfl_xor(acc, 16, 64);
  acc += __shfl_xor(acc, 32, 64);
  __shared__ float sm[4];
  if (lane == 0) sm[wave] = acc;
  __syncthreads();
  if (tid == 0) {
    const float partial = (sm[0] + sm[1]) + (sm[2] + sm[3]);
    // per-sample loss >= -8 -> partial >= -2048; bias 2100 keeps fx >= 0.
    // scale 2^18; total < 2048*2^32 << 2^52 -> no carry into the count field.
    const unsigned long long fx =
        (unsigned long long)((partial + 2100.0f) * 262144.0f + 0.5f);
    const unsigned long long mine = (1ULL << 52) + fx;
    const unsigned long long old  = atomicAdd(acc64, mine);
    const unsigned long long tot  = old + mine;
    if ((tot >> 52) == (unsigned long long)GRID1) {
      const double s = (double)(tot & ((1ULL << 52) - 1)) * (1.0 / 262144.0)
                     - 2100.0 * (double)GRID1;
      out[0] = (float)(s / (double)BROWS);
    }
  }
}

extern "C" void kernel_launch(void* const* d_in, const int* in_sizes, int n_in,
                              void* d_out, int out_size, void* d_ws, size_t ws_size,
                              hipStream_t stream) {
  const float* inp = (const float*)d_in[0];
  const float* y   = (const float*)d_in[1];
  const int*   e   = (const int*)d_in[2];
  float* out = (float*)d_out;
  unsigned long long* acc64 = (unsigned long long*)d_ws;

  hipMemsetAsync(acc64, 0, sizeof(unsigned long long), stream);
  surv_main<<<GRID1, 256, 0, stream>>>(inp, y, e, out, acc64);
}

// Round 8
// 51.786 us; speedup vs baseline: 1.1299x; 1.1299x over previous
//
#include <hip/hip_runtime.h>

#define BROWS 524288
#define KBINS 64
#define GRID1 2048
// rows per block per outer iteration: 4 waves * 8 rows = 32 -> 8 iterations
#define ITERS (BROWS / (GRID1 * 32))

typedef float v4f __attribute__((ext_vector_type(4)));

// DPP row_shr add: val += lanes shifted right by n within each 16-lane row.
// bound_ctrl=1 -> out-of-range lanes contribute 0. Pure VALU (no LDS pipe).
#define DPP_ADD(val, ctrl)                                                 \
  do {                                                                     \
    int _s = __builtin_amdgcn_update_dpp(                                  \
        0, __builtin_bit_cast(int, (val)), (ctrl), 0xf, 0xf, true);        \
    (val) += __builtin_bit_cast(float, _s);                                \
  } while (0)
#define ROW_SHR1 0x111
#define ROW_SHR2 0x112
#define ROW_SHR4 0x114
#define ROW_SHR8 0x118

__global__ __launch_bounds__(256) void surv_main(
    const float* __restrict__ inp, const float* __restrict__ yv,
    const int* __restrict__ ev, float* __restrict__ out,
    float* __restrict__ partials)
{
  const int tid  = threadIdx.x;
  const int lane = tid & 63;
  const int wave = tid >> 6;   // 0..3
  const int sub  = lane >> 4;  // row within 4-row group
  const int l16  = lane & 15;  // lane within row group

  const float A   = 2.8853900817779268f;   // 2*log2(e)  (logit scale, log2 domain)
  const float M2  = 0.28853900817779268f;  // 0.2*log2(e) (margin*scale, log2 domain)
  const float S0  = 0.018315638888734179f; // exp(-4)
  const float IS0 = 54.598150033144236f;   // exp(+4)
  const float LN2 = 0.6931471805599453f;

  float acc = 0.f;

  for (int it = 0; it < ITERS; ++it) {
    const int base = (it * GRID1 + blockIdx.x) * 32 + wave * 8;
    const int row0 = base + sub;
    const int row1 = base + 4 + sub;

    // hoist loads: both rows' y/e/x plus prev-row y/e (same cache lines)
    const int rp0 = row0 ? row0 - 1 : 0;   // clamp only hit at global row 0
    const int rp1 = row1 - 1;
    const float y0 = yv[row0], y1 = yv[row1];
    const int   e0 = ev[row0], e1 = ev[row1];
    const float yp0 = yv[rp0], yp1 = yv[rp1];
    const int   ep0 = ev[rp0], ep1 = ev[rp1];
    const float4 x0 = *reinterpret_cast<const float4*>(
        inp + (size_t)row0 * KBINS + l16 * 4);
    const float4 x1 = *reinterpret_cast<const float4*>(
        inp + (size_t)row1 * KBINS + l16 * 4);

    #pragma unroll
    for (int h = 0; h < 2; ++h) {
      const int   row = h ? row1 : row0;
      const float y   = h ? y1 : y0;
      const int   e   = h ? e1 : e0;
      const float yp  = h ? yp1 : yp0;
      const int   ep  = h ? ep1 : ep0;
      const float4 x  = h ? x1 : x0;

      const int   b = (int)y;
      const bool valid = (y >= 0.f) && (y < 64.f);
      const int b_eff = valid ? b : 127;              // sentinel: c==0 everywhere
      const int hi    = (e != 0) ? b_eff : 63;        // count = [b_eff, hi]
      const bool all1 = (e == 0) && (b_eff == 0);     // count all-ones -> min==1
      const float m_in = all1 ? M2 : 0.f;             // margin on count==1 bins

      // prev row's bin-63 count: 1 iff (e!=0 && b==63) or (e==0 && valid)
      const int   bp = (int)yp;
      const bool  vp = (yp >= 0.f) && (yp < 64.f);
      const float c63p = (ep != 0) ? ((vp && bp == 63) ? 1.f : 0.f)
                                   : (vp ? 1.f : 0.f);

      const float xa[4] = {x.x, x.y, x.z, x.w};
      float correct = 0.f, fev = 0.f, fcs = 0.f;
      float c[4];
      #pragma unroll
      for (int j = 0; j < 4; ++j) {
        const int bin = l16 * 4 + j;
        const bool cb = (bin >= b_eff) && (bin <= hi);
        const float mm = cb ? m_in : M2;
        const float t  = fmaf(xa[j], A, mm);           // log2-domain logit
        const float pen = __builtin_amdgcn_exp2f(t);   // exp(+logit)
        const float pe  = __builtin_amdgcn_exp2f(-t);  // exp(-logit)
        correct += cb ? pe  : 0.f;
        fcs     += cb ? 0.f : pe;
        fev     += cb ? 0.f : pen;
        c[j] = cb ? 1.f : 0.f;
      }

      // aligned shifted-window store (round 6): lane covers bins l16*4-1..+2;
      // out[0] gets garbage, overwritten by surv_reduce afterwards.
      {
        const int  binm1 = l16 * 4 - 1;
        const bool cm1 = (binm1 >= b_eff) && (binm1 <= hi);
        v4f cv;
        cv[0] = (l16 == 0) ? c63p : (cm1 ? 1.f : 0.f);
        cv[1] = c[0]; cv[2] = c[1]; cv[3] = c[2];
        *reinterpret_cast<v4f*>(out + (size_t)row * KBINS + l16 * 4) = cv;
        if (row == BROWS - 1 && l16 == 15)
          out[(size_t)BROWS * KBINS] = c[3];           // count[B-1][63]
      }

      // 16-lane reduction on the VALU pipe via DPP row_shr; sum -> lane 15
      DPP_ADD(correct, ROW_SHR1); DPP_ADD(fev, ROW_SHR1); DPP_ADD(fcs, ROW_SHR1);
      DPP_ADD(correct, ROW_SHR2); DPP_ADD(fev, ROW_SHR2); DPP_ADD(fcs, ROW_SHR2);
      DPP_ADD(correct, ROW_SHR4); DPP_ADD(fev, ROW_SHR4); DPP_ADD(fcs, ROW_SHR4);
      DPP_ADD(correct, ROW_SHR8); DPP_ADD(fev, ROW_SHR8); DPP_ADD(fcs, ROW_SHR8);

      // sum(count)==1  <=>  valid && (event || b==K-1)
      const bool is_event = valid && (e != 0 || b == KBINS - 1);
      // lev: log(a)+log(b) = LN2*log2(a*b) -> one transcendental
      const float lev = __builtin_amdgcn_logf((correct + S0) * (fev + S0)) * LN2;
      const float lcs = __builtin_amdgcn_logf(
                            fmaf(fcs, IS0, fmaf(correct, fcs, 1.f))) * LN2;
      if (l16 == 15) acc += is_event ? lev : lcs;      // owner = lane 15 (DPP)
    }
  }

  // block reduction: acc nonzero at lanes {15,31,47,63}
  acc += __shfl_xor(acc, 16, 64);
  acc += __shfl_xor(acc, 32, 64);
  __shared__ float sm[4];
  if (lane == 15) sm[wave] = acc;
  __syncthreads();
  if (tid == 0) partials[blockIdx.x] = (sm[0] + sm[1]) + (sm[2] + sm[3]);
}

__global__ __launch_bounds__(256) void surv_reduce(
    const float* __restrict__ partials, float* __restrict__ out)
{
  __shared__ float sm[256];
  float s = 0.f;
  for (int i = threadIdx.x; i < GRID1; i += 256) s += partials[i];
  sm[threadIdx.x] = s;
  __syncthreads();
  for (int o = 128; o > 0; o >>= 1) {
    if (threadIdx.x < o) sm[threadIdx.x] += sm[threadIdx.x + o];
    __syncthreads();
  }
  if (threadIdx.x == 0) out[0] = sm[0] * (1.0f / (float)BROWS);
}

extern "C" void kernel_launch(void* const* d_in, const int* in_sizes, int n_in,
                              void* d_out, int out_size, void* d_ws, size_t ws_size,
                              hipStream_t stream) {
  const float* inp = (const float*)d_in[0];
  const float* y   = (const float*)d_in[1];
  const int*   e   = (const int*)d_in[2];
  float* out      = (float*)d_out;
  float* partials = (float*)d_ws;   // GRID1 floats

  surv_main<<<GRID1, 256, 0, stream>>>(inp, y, e, out, partials);
  surv_reduce<<<1, 256, 0, stream>>>(partials, out);
}

// Round 9
// 48.000 us; speedup vs baseline: 1.2190x; 1.0789x over previous
//
#include <hip/hip_runtime.h>

#define BROWS 524288
#define KBINS 64
#define GRID1 2048
// rows per block per outer iteration: 4 waves * 8 rows = 32 -> 8 iterations
#define ITERS (BROWS / (GRID1 * 32))

typedef float v4f __attribute__((ext_vector_type(4)));

// DPP row_shr add: val += lanes shifted right by n within each 16-lane row.
// bound_ctrl=1 -> out-of-range lanes contribute 0. Pure VALU (no LDS pipe).
#define DPP_ADD(val, ctrl)                                                 \
  do {                                                                     \
    int _s = __builtin_amdgcn_update_dpp(                                  \
        0, __builtin_bit_cast(int, (val)), (ctrl), 0xf, 0xf, true);        \
    (val) += __builtin_bit_cast(float, _s);                                \
  } while (0)
#define ROW_SHR1 0x111
#define ROW_SHR2 0x112
#define ROW_SHR4 0x114
#define ROW_SHR8 0x118

__global__ __launch_bounds__(256) void surv_main(
    const float* __restrict__ inp, const float* __restrict__ yv,
    const int* __restrict__ ev, float* __restrict__ out,
    float* __restrict__ partials)
{
  const int tid  = threadIdx.x;
  const int lane = tid & 63;
  const int wave = tid >> 6;   // 0..3
  const int sub  = lane >> 4;  // row within 4-row group
  const int l16  = lane & 15;  // lane within row group

  const float A   = 2.8853900817779268f;   // 2*log2(e)  (logit scale, log2 domain)
  const float M2  = 0.28853900817779268f;  // 0.2*log2(e) (margin*scale, log2 domain)
  const float S0  = 0.018315638888734179f; // exp(-4)
  const float IS0 = 54.598150033144236f;   // exp(+4)
  const float LN2 = 0.6931471805599453f;

  float acc = 0.f;

  for (int it = 0; it < ITERS; ++it) {
    const int base = (it * GRID1 + blockIdx.x) * 32 + wave * 8;
    const int row0 = base + sub;
    const int row1 = base + 4 + sub;

    // hoist loads: both rows' y/e/x plus prev-row y/e (same cache lines)
    const int rp0 = row0 ? row0 - 1 : 0;   // clamp only hit at global row 0
    const int rp1 = row1 - 1;
    const float y0 = yv[row0], y1 = yv[row1];
    const int   e0 = ev[row0], e1 = ev[row1];
    const float yp0 = yv[rp0], yp1 = yv[rp1];
    const int   ep0 = ev[rp0], ep1 = ev[rp1];
    const float4 x0 = *reinterpret_cast<const float4*>(
        inp + (size_t)row0 * KBINS + l16 * 4);
    const float4 x1 = *reinterpret_cast<const float4*>(
        inp + (size_t)row1 * KBINS + l16 * 4);

    #pragma unroll
    for (int h = 0; h < 2; ++h) {
      const int   row = h ? row1 : row0;
      const float y   = h ? y1 : y0;
      const int   e   = h ? e1 : e0;
      const float yp  = h ? yp1 : yp0;
      const int   ep  = h ? ep1 : ep0;
      const float4 x  = h ? x1 : x0;

      const int   b = (int)y;
      const bool valid = (y >= 0.f) && (y < 64.f);
      const int b_eff = valid ? b : 127;              // sentinel: c==0 everywhere
      const int hi    = (e != 0) ? b_eff : 63;        // count = [b_eff, hi]
      const bool all1 = (e == 0) && (b_eff == 0);     // count all-ones -> min==1
      const float m_in = all1 ? M2 : 0.f;             // margin on count==1 bins

      // prev row's bin-63 count: 1 iff (e!=0 && b==63) or (e==0 && valid)
      const int   bp = (int)yp;
      const bool  vp = (yp >= 0.f) && (yp < 64.f);
      const float c63p = (ep != 0) ? ((vp && bp == 63) ? 1.f : 0.f)
                                   : (vp ? 1.f : 0.f);

      const float xa[4] = {x.x, x.y, x.z, x.w};
      float correct = 0.f, fev = 0.f, fcs = 0.f;
      float c[4];
      #pragma unroll
      for (int j = 0; j < 4; ++j) {
        const int bin = l16 * 4 + j;
        const bool cb = (bin >= b_eff) && (bin <= hi);
        const float mm = cb ? m_in : M2;
        const float t  = fmaf(xa[j], A, mm);           // log2-domain logit
        const float pen = __builtin_amdgcn_exp2f(t);   // exp(+logit)
        const float pe  = __builtin_amdgcn_exp2f(-t);  // exp(-logit)
        correct += cb ? pe  : 0.f;
        fcs     += cb ? 0.f : pe;
        fev     += cb ? 0.f : pen;
        c[j] = cb ? 1.f : 0.f;
      }

      // aligned shifted-window store (round 6), now NONTEMPORAL: the count
      // stream is write-once/never-read; bypassing L2/L3 keeps the input
      // L3-resident across replays. Each wave's store = 1024B line-aligned
      // contiguous -> perfect write combining. out[0] garbage, overwritten
      // by surv_reduce.
      {
        const int  binm1 = l16 * 4 - 1;
        const bool cm1 = (binm1 >= b_eff) && (binm1 <= hi);
        v4f cv;
        cv[0] = (l16 == 0) ? c63p : (cm1 ? 1.f : 0.f);
        cv[1] = c[0]; cv[2] = c[1]; cv[3] = c[2];
        __builtin_nontemporal_store(
            cv, reinterpret_cast<v4f*>(out + (size_t)row * KBINS + l16 * 4));
        if (row == BROWS - 1 && l16 == 15)
          __builtin_nontemporal_store(c[3], out + (size_t)BROWS * KBINS);
      }

      // 16-lane reduction on the VALU pipe via DPP row_shr; sum -> lane 15
      DPP_ADD(correct, ROW_SHR1); DPP_ADD(fev, ROW_SHR1); DPP_ADD(fcs, ROW_SHR1);
      DPP_ADD(correct, ROW_SHR2); DPP_ADD(fev, ROW_SHR2); DPP_ADD(fcs, ROW_SHR2);
      DPP_ADD(correct, ROW_SHR4); DPP_ADD(fev, ROW_SHR4); DPP_ADD(fcs, ROW_SHR4);
      DPP_ADD(correct, ROW_SHR8); DPP_ADD(fev, ROW_SHR8); DPP_ADD(fcs, ROW_SHR8);

      // sum(count)==1  <=>  valid && (event || b==K-1)
      const bool is_event = valid && (e != 0 || b == KBINS - 1);
      // lev: log(a)+log(b) = LN2*log2(a*b) -> one transcendental
      const float lev = __builtin_amdgcn_logf((correct + S0) * (fev + S0)) * LN2;
      const float lcs = __builtin_amdgcn_logf(
                            fmaf(fcs, IS0, fmaf(correct, fcs, 1.f))) * LN2;
      if (l16 == 15) acc += is_event ? lev : lcs;      // owner = lane 15 (DPP)
    }
  }

  // block reduction: acc nonzero at lanes {15,31,47,63}
  acc += __shfl_xor(acc, 16, 64);
  acc += __shfl_xor(acc, 32, 64);
  __shared__ float sm[4];
  if (lane == 15) sm[wave] = acc;
  __syncthreads();
  if (tid == 0) partials[blockIdx.x] = (sm[0] + sm[1]) + (sm[2] + sm[3]);
}

__global__ __launch_bounds__(256) void surv_reduce(
    const float* __restrict__ partials, float* __restrict__ out)
{
  __shared__ float sm[256];
  float s = 0.f;
  for (int i = threadIdx.x; i < GRID1; i += 256) s += partials[i];
  sm[threadIdx.x] = s;
  __syncthreads();
  for (int o = 128; o > 0; o >>= 1) {
    if (threadIdx.x < o) sm[threadIdx.x] += sm[threadIdx.x + o];
    __syncthreads();
  }
  if (threadIdx.x == 0) out[0] = sm[0] * (1.0f / (float)BROWS);
}

extern "C" void kernel_launch(void* const* d_in, const int* in_sizes, int n_in,
                              void* d_out, int out_size, void* d_ws, size_t ws_size,
                              hipStream_t stream) {
  const float* inp = (const float*)d_in[0];
  const float* y   = (const float*)d_in[1];
  const int*   e   = (const int*)d_in[2];
  float* out      = (float*)d_out;
  float* partials = (float*)d_ws;   // GRID1 floats

  surv_main<<<GRID1, 256, 0, stream>>>(inp, y, e, out, partials);
  surv_reduce<<<1, 256, 0, stream>>>(partials, out);
}